// Round 2
// baseline (600.032 us; speedup 1.0000x reference)
//
#include <hip/hip_runtime.h>
#include <math.h>

// Problem constants
#define NROWS 32768       // B*H*W
#define KCODES 1024
#define DDIM 256
#define BM 32             // rows per block
#define QUANT_OFF 1                    // out offsets: loss@0, quant@1
#define PERP_OFF  8388609
#define ENC_OFF   8388610
#define EPACK_OFF 4096                 // ws float offset of packed e (uint4 units)

// ws layout (floats): [0,1024) e2 norms, [1024,2048) counts, [2048] kld_sum,
// [2049] elat_sum, [4096, 4096+262144) packed fp16 hi/lo codebook (1 MB).
// epack unit index: ((part*16 + ks)*2 + kg)*1024 + n   (uint4 = 8 halves, d = ks*16+kg*8+j)

typedef _Float16 f16x8 __attribute__((ext_vector_type(8)));
typedef float    f32x16 __attribute__((ext_vector_type(16)));

__global__ void __launch_bounds__(256)
vq_setup(const float* __restrict__ emb, float* __restrict__ ws) {
    int k = blockIdx.x * 256 + threadIdx.x;
    if (k < KCODES) {
        const float* row = emb + (size_t)k * DDIM;
        float s = 0.f;
        #pragma unroll 4
        for (int c = 0; c < DDIM; c += 4) {
            float4 v = *(const float4*)(row + c);
            s = fmaf(v.x, v.x, s); s = fmaf(v.y, v.y, s);
            s = fmaf(v.z, v.z, s); s = fmaf(v.w, v.w, s);
        }
        ws[k] = s;
        ws[KCODES + k] = 0.f;
        if (k == 0) { ws[2 * KCODES] = 0.f; ws[2 * KCODES + 1] = 0.f; }
    }
}

// pre-pack codebook into MFMA-B-fragment-ready fp16 hi/lo units
__global__ void __launch_bounds__(256)
vq_pack(const float* __restrict__ emb, float* __restrict__ ws) {
    int u = blockIdx.x * 256 + threadIdx.x;      // 65536 units
    int n    = u & 1023;
    int kg   = (u >> 10) & 1;
    int ks   = (u >> 11) & 15;
    int part = (u >> 15) & 1;
    int d0 = ks * 16 + kg * 8;
    const float* src = emb + (size_t)n * DDIM + d0;
    float4 v0 = *(const float4*)(src);
    float4 v1 = *(const float4*)(src + 4);
    float x[8] = {v0.x, v0.y, v0.z, v0.w, v1.x, v1.y, v1.z, v1.w};
    union { _Float16 h[8]; uint4 q; } p;
    #pragma unroll
    for (int j = 0; j < 8; ++j) {
        _Float16 hh = (_Float16)x[j];
        p.h[j] = part ? (_Float16)(x[j] - (float)hh) : hh;
    }
    ((uint4*)(ws + EPACK_OFF))[u] = p.q;
}

__global__ void __launch_bounds__(256, 2)
vq_main(const float* __restrict__ inp, const float* __restrict__ emb,
        const float* __restrict__ gmb, float* __restrict__ out,
        float* __restrict__ ws) {
    __shared__ float xs[DDIM][BM + 4];     // 36.9 KB, x tile transposed [d][row]
    __shared__ uint4 apack[2048];          // 32 KB: A frags [part][ks16][kg2][row32]
    __shared__ float xn2p[8][BM];
    __shared__ float xn2[BM];
    __shared__ float rrv[BM][4];
    __shared__ int   rri[BM][4];
    __shared__ int   idxs[BM];
    __shared__ float redK[4], redE[4];

    const int tid  = threadIdx.x;
    const int lane = tid & 63;
    const int wv   = tid >> 6;    // wave 0..3, owns cols [wv*256, wv*256+256)
    const int lrow = lane & 31;   // MFMA m/n lane index
    const int lkg  = lane >> 5;   // MFMA k-group
    const int n0   = blockIdx.x * BM;
    const int b    = n0 >> 10;    // HW = 1024, block never straddles b
    const int s0   = n0 & 1023;

    const float* e2     = ws;
    float*       counts = ws + KCODES;
    const uint4* ep     = (const uint4*)(ws + EPACK_OFF);

    // ---- stage x tile: inputs[b][c][s0+r] -> xs[c][r] (coalesced)
    {
        const float* base = inp + ((size_t)b * DDIM) * 1024 + s0;
        for (int t = tid; t < DDIM * BM; t += 256) {
            int r = t & 31, c = t >> 5;
            xs[c][r] = base[(size_t)c * 1024 + r];
        }
    }
    __syncthreads();

    // ---- convert x -> fp16 hi/lo A-fragments + per-row norm partials
    {
        const int row = tid & 31;
        const int sec = tid >> 5;          // 0..7, covers d in [sec*32, sec*32+32)
        float s = 0.f;
        #pragma unroll
        for (int half = 0; half < 2; ++half) {
            const int ks = sec * 2 + half;
            #pragma unroll
            for (int kg = 0; kg < 2; ++kg) {
                union { _Float16 h[8]; uint4 q; } ph, pl;
                #pragma unroll
                for (int j = 0; j < 8; ++j) {
                    float x = xs[ks * 16 + kg * 8 + j][row];
                    s = fmaf(x, x, s);
                    _Float16 hh = (_Float16)x;
                    ph.h[j] = hh;
                    pl.h[j] = (_Float16)(x - (float)hh);
                }
                apack[(ks * 2 + kg) * 32 + row]        = ph.q;
                apack[((16 + ks) * 2 + kg) * 32 + row] = pl.q;
            }
        }
        xn2p[sec][row] = s;
    }
    __syncthreads();
    if (tid < BM) {
        float s = 0.f;
        #pragma unroll
        for (int p = 0; p < 8; ++p) s += xn2p[p][tid];
        xn2[tid] = s;
    }
    __syncthreads();

    // ---- barrier-free MFMA K-loop: acc[nt] = x . e^T for cols wv*256 + nt*32 + lrow
    f32x16 acc[8];
    #pragma unroll
    for (int nt = 0; nt < 8; ++nt)
        #pragma unroll
        for (int e = 0; e < 16; ++e) acc[nt][e] = 0.f;

    #pragma unroll 2
    for (int ks = 0; ks < 16; ++ks) {
        f16x8 ah = *(const f16x8*)&apack[(ks * 2 + lkg) * 32 + lrow];
        f16x8 al = *(const f16x8*)&apack[((16 + ks) * 2 + lkg) * 32 + lrow];
        const uint4* bh = ep + (size_t)(ks * 2048 + lkg * 1024 + wv * 256 + lrow);
        const uint4* bl = bh + 32768;
        #pragma unroll
        for (int nt = 0; nt < 8; ++nt) {
            f16x8 Bh = *(const f16x8*)(bh + nt * 32);
            f16x8 Bl = *(const f16x8*)(bl + nt * 32);
            acc[nt] = __builtin_amdgcn_mfma_f32_32x32x16_f16(ah, Bh, acc[nt], 0, 0, 0);
            acc[nt] = __builtin_amdgcn_mfma_f32_32x32x16_f16(ah, Bl, acc[nt], 0, 0, 0);
            acc[nt] = __builtin_amdgcn_mfma_f32_32x32x16_f16(al, Bh, acc[nt], 0, 0, 0);
        }
    }

    // ---- epilogue: distances, gumbel argmax, KLD
    // D layout (m101-verified): col = lane&31, row = (reg&3) + 8*(reg>>2) + 4*(lane>>5)
    float xnr[16];
    #pragma unroll
    for (int reg = 0; reg < 16; ++reg)
        xnr[reg] = xn2[(reg & 3) + 8 * (reg >> 2) + 4 * lkg];

    float rv[16]; int ri[16];
    #pragma unroll
    for (int reg = 0; reg < 16; ++reg) { rv[reg] = -1e30f; ri[reg] = 0; }
    float kld_acc = 0.f;

    #pragma unroll
    for (int nt = 0; nt < 8; ++nt) {
        const int col = wv * 256 + nt * 32 + lrow;
        const float e2c = e2[col];
        const float* gcol = gmb + ((size_t)n0 << 10) + col;
        #pragma unroll
        for (int reg = 0; reg < 16; ++reg) {
            const int row = (reg & 3) + 8 * (reg >> 2) + 4 * lkg;
            float dist = xnr[reg] + e2c - 2.f * acc[nt][reg];
            float g    = gcol[(size_t)row << 10];
            float val  = g - dist;
            if (val > rv[reg]) { rv[reg] = val; ri[reg] = col; } // cols ascend per thread
            float p = 1.f / (1.f + __expf(dist));
            kld_acc += p * __logf(fmaxf(p, 1e-8f));
        }
    }

    // ---- per-row argmax: reduce across the 32 col-lanes (first-index tie-break)
    #pragma unroll
    for (int reg = 0; reg < 16; ++reg) {
        float v = rv[reg];
        int   c = ri[reg];
        #pragma unroll
        for (int off = 16; off > 0; off >>= 1) {
            float ov = __shfl_xor(v, off, 64);
            int   oc = __shfl_xor(c, off, 64);
            if (ov > v || (ov == v && oc < c)) { v = ov; c = oc; }
        }
        if (lrow == 0) {
            int row = (reg & 3) + 8 * (reg >> 2) + 4 * lkg;
            rrv[row][wv] = v;
            rri[row][wv] = c;
        }
    }
    __syncthreads();
    // combine the 4 waves' partials (wave order = ascending col ranges)
    if (tid < BM) {
        float bv = rrv[tid][0]; int bc = rri[tid][0];
        #pragma unroll
        for (int w = 1; w < 4; ++w) {
            float v = rrv[tid][w]; int c = rri[tid][w];
            if (v > bv || (v == bv && c < bc)) { bv = v; bc = c; }
        }
        idxs[tid] = bc;
        atomicAdd(&counts[bc], 1.0f);
    }
    __syncthreads();

    // ---- encodings: one-hot, fully coalesced float4 stores
    {
        float* enc = out + ENC_OFF;
        for (int t = tid; t < BM * (KCODES / 4); t += 256) {
            int c4 = t & 255, row = t >> 8;
            int base = c4 * 4;
            int id = idxs[row];
            float4 v;
            v.x = (base + 0 == id) ? 1.f : 0.f;
            v.y = (base + 1 == id) ? 1.f : 0.f;
            v.z = (base + 2 == id) ? 1.f : 0.f;
            v.w = (base + 3 == id) ? 1.f : 0.f;
            *(float4*)(enc + ((size_t)(n0 + row) << 10) + base) = v;
        }
    }

    // ---- quantized gather + store (NCHW) + e_latent partial
    float elat_acc = 0.f;
    {
        float* outq = out + QUANT_OFF;
        for (int t = tid; t < DDIM * (BM / 4); t += 256) {  // (c, r4)
            int r4 = t & 7, c = t >> 3;
            float4 xv = *(const float4*)&xs[c][r4 * 4];
            float q0 = emb[(size_t)idxs[r4 * 4 + 0] * DDIM + c];
            float q1 = emb[(size_t)idxs[r4 * 4 + 1] * DDIM + c];
            float q2 = emb[(size_t)idxs[r4 * 4 + 2] * DDIM + c];
            float q3 = emb[(size_t)idxs[r4 * 4 + 3] * DDIM + c];
            float d0 = q0 - xv.x, d1 = q1 - xv.y, d2 = q2 - xv.z, d3 = q3 - xv.w;
            elat_acc = fmaf(d0, d0, elat_acc);
            elat_acc = fmaf(d1, d1, elat_acc);
            elat_acc = fmaf(d2, d2, elat_acc);
            elat_acc = fmaf(d3, d3, elat_acc);
            float4 qv = make_float4(q0, q1, q2, q3);
            *(float4*)(outq + (((size_t)(b * DDIM + c)) << 10) + s0 + r4 * 4) = qv;
        }
    }

    // ---- block-reduce kld & elat, one atomic each per block
    #pragma unroll
    for (int off = 32; off > 0; off >>= 1) {
        kld_acc  += __shfl_xor(kld_acc, off);
        elat_acc += __shfl_xor(elat_acc, off);
    }
    if ((tid & 63) == 0) { redK[wv] = kld_acc; redE[wv] = elat_acc; }
    __syncthreads();
    if (tid == 0) {
        atomicAdd(&ws[2 * KCODES],     redK[0] + redK[1] + redK[2] + redK[3]);
        atomicAdd(&ws[2 * KCODES + 1], redE[0] + redE[1] + redE[2] + redE[3]);
    }
}

__global__ void __launch_bounds__(256)
vq_finalize(const float* __restrict__ ws, float* __restrict__ out) {
    __shared__ float red[4];
    int tid = threadIdx.x;
    float s = 0.f;
    for (int k = tid; k < KCODES; k += 256) {
        float avg = ws[KCODES + k] * (1.f / (float)NROWS);
        s += avg * logf(avg + 1e-10f);
    }
    #pragma unroll
    for (int off = 32; off > 0; off >>= 1) s += __shfl_xor(s, off);
    if ((tid & 63) == 0) red[tid >> 6] = s;
    __syncthreads();
    if (tid == 0) {
        float ssum = red[0] + red[1] + red[2] + red[3];
        float perp = expf(-ssum);
        float kld  = ws[2 * KCODES]     / (float)NROWS;
        float elat = ws[2 * KCODES + 1] / (float)(NROWS * DDIM);
        float ratio = kld / fmaxf(elat, 1e-8f);
        float loss  = 1.5f * (kld + elat * ratio);
        out[0]        = loss;
        out[PERP_OFF] = perp;
    }
}

extern "C" void kernel_launch(void* const* d_in, const int* in_sizes, int n_in,
                              void* d_out, int out_size, void* d_ws, size_t ws_size,
                              hipStream_t stream) {
    const float* inp = (const float*)d_in[0];   // [32,256,32,32]
    const float* emb = (const float*)d_in[1];   // [1024,256]
    const float* gmb = (const float*)d_in[2];   // [32768,1024]
    float* out = (float*)d_out;
    float* ws  = (float*)d_ws;

    vq_setup<<<dim3(KCODES / 256), dim3(256), 0, stream>>>(emb, ws);
    vq_pack<<<dim3(256), dim3(256), 0, stream>>>(emb, ws);
    vq_main<<<dim3(NROWS / BM), dim3(256), 0, stream>>>(inp, emb, gmb, out, ws);
    vq_finalize<<<dim3(1), dim3(256), 0, stream>>>(ws, out);
}

// Round 3
// 402.174 us; speedup vs baseline: 1.4920x; 1.4920x over previous
//
#include <hip/hip_runtime.h>
#include <math.h>

// Problem constants
#define NROWS 32768       // B*H*W
#define KCODES 1024
#define DDIM 256
#define BM 32             // rows per block
#define QUANT_OFF 1                    // out offsets: loss@0, quant@1
#define PERP_OFF  8388609
#define ENC_OFF   8388610
#define EPACK_OFF 4096                 // ws float offset of packed e (16B units)

// ws layout (floats): [0,1024) e2 norms, [1024,2048) counts, [2048] kld_sum,
// [2049] elat_sum, [4096, 4096+262144) packed fp16 hi/lo codebook (1 MB).
// epack unit index: ((part*16 + ks)*2 + kg)*1024 + n   (unit = 8 halves, d = ks*16+kg*8+j)

typedef _Float16 f16x8 __attribute__((ext_vector_type(8)));
typedef float    f32x16 __attribute__((ext_vector_type(16)));

__global__ void __launch_bounds__(256)
vq_setup(const float* __restrict__ emb, float* __restrict__ ws) {
    int k = blockIdx.x * 256 + threadIdx.x;
    if (k < KCODES) {
        const float* row = emb + (size_t)k * DDIM;
        float s = 0.f;
        #pragma unroll 4
        for (int c = 0; c < DDIM; c += 4) {
            float4 v = *(const float4*)(row + c);
            s = fmaf(v.x, v.x, s); s = fmaf(v.y, v.y, s);
            s = fmaf(v.z, v.z, s); s = fmaf(v.w, v.w, s);
        }
        ws[k] = s;
        ws[KCODES + k] = 0.f;
        if (k == 0) { ws[2 * KCODES] = 0.f; ws[2 * KCODES + 1] = 0.f; }
    }
}

// pre-pack codebook into MFMA-B-fragment-ready fp16 hi/lo units
__global__ void __launch_bounds__(256)
vq_pack(const float* __restrict__ emb, float* __restrict__ ws) {
    int u = blockIdx.x * 256 + threadIdx.x;      // 65536 units
    int n    = u & 1023;
    int kg   = (u >> 10) & 1;
    int ks   = (u >> 11) & 15;
    int part = (u >> 15) & 1;
    int d0 = ks * 16 + kg * 8;
    const float* src = emb + (size_t)n * DDIM + d0;
    float4 v0 = *(const float4*)(src);
    float4 v1 = *(const float4*)(src + 4);
    float x[8] = {v0.x, v0.y, v0.z, v0.w, v1.x, v1.y, v1.z, v1.w};
    union { _Float16 h[8]; uint4 q; } p;
    #pragma unroll
    for (int j = 0; j < 8; ++j) {
        _Float16 hh = (_Float16)x[j];
        p.h[j] = part ? (_Float16)(x[j] - (float)hh) : hh;
    }
    ((uint4*)(ws + EPACK_OFF))[u] = p.q;
}

__global__ void __launch_bounds__(256, 3)
vq_main(const float* __restrict__ inp, const float* __restrict__ emb,
        const float* __restrict__ gmb, float* __restrict__ out,
        float* __restrict__ ws) {
    __shared__ uint4 apack[2048];          // 32 KB: A frags [part2][ks16][kg2][row32]
    __shared__ float xchunk[64][33];       // 8.25 KB staging (64 d x 32 rows)
    __shared__ float xn2p[8][BM];
    __shared__ float xn2[BM];
    __shared__ float rrv[BM][4];
    __shared__ int   rri[BM][4];
    __shared__ int   idxs[BM];
    __shared__ float redK[4], redE[4];

    const int tid  = threadIdx.x;
    const int lane = tid & 63;
    const int wv   = tid >> 6;    // wave 0..3, owns cols [wv*256, wv*256+256)
    const int lrow = lane & 31;   // MFMA m/n lane index
    const int lkg  = lane >> 5;   // MFMA k-group
    const int n0   = blockIdx.x * BM;
    const int b    = n0 >> 10;    // HW = 1024, block never straddles b
    const int s0   = n0 & 1023;

    const float* e2     = ws;
    float*       counts = ws + KCODES;
    const f16x8* ep     = (const f16x8*)(ws + EPACK_OFF);

    // ---- convert x -> fp16 hi/lo A-fragments via 64-d staging chunks ----
    const int crow = tid & 31;
    const int ckg  = (tid >> 5) & 1;
    const int cksl = tid >> 6;           // 0..3
    float xsq = 0.f;
    const float* xbase = inp + (((size_t)b * DDIM) << 10) + s0;

    #pragma unroll 1
    for (int cb = 0; cb < 4; ++cb) {
        #pragma unroll
        for (int t0 = 0; t0 < 8; ++t0) {
            int t = tid + t0 * 256;
            int r = t & 31, dd = t >> 5;
            xchunk[dd][r] = xbase[(((size_t)(cb * 64 + dd)) << 10) + r];
        }
        __syncthreads();
        {
            union { _Float16 h[8]; uint4 q; } ph, pl;
            #pragma unroll
            for (int j = 0; j < 8; ++j) {
                float x = xchunk[cksl * 16 + ckg * 8 + j][crow];
                xsq = fmaf(x, x, xsq);
                _Float16 hh = (_Float16)x;
                ph.h[j] = hh;
                pl.h[j] = (_Float16)(x - (float)hh);
            }
            int ks = cb * 4 + cksl;
            apack[(ks * 2 + ckg) * 32 + crow]        = ph.q;
            apack[((16 + ks) * 2 + ckg) * 32 + crow] = pl.q;
        }
        __syncthreads();
    }
    xn2p[tid >> 5][crow] = xsq;
    __syncthreads();
    if (tid < BM) {
        float s = 0.f;
        #pragma unroll
        for (int p = 0; p < 8; ++p) s += xn2p[p][tid];
        xn2[tid] = s;
    }
    __syncthreads();

    // ---- MFMA main loop: 4 pairs of 32-col tiles per wave, fused epilogue ----
    float rv[16]; int ri[16];
    #pragma unroll
    for (int reg = 0; reg < 16; ++reg) { rv[reg] = -1e30f; ri[reg] = 0; }
    float kld_acc = 0.f;

    #pragma unroll 1
    for (int np = 0; np < 4; ++np) {
        const int c0 = wv * 256 + np * 64 + lrow;     // tile0 col for this lane
        const float* gb = gmb + ((size_t)n0 << 10) + c0;

        // prefetch gumbel for tile0 (consumed after the K-loop)
        float g0r[16];
        #pragma unroll
        for (int reg = 0; reg < 16; ++reg) {
            int row = (reg & 3) + 8 * (reg >> 2) + 4 * lkg;
            g0r[reg] = gb[(size_t)row << 10];
        }

        f32x16 acc0, acc1;
        #pragma unroll
        for (int e = 0; e < 16; ++e) { acc0[e] = 0.f; acc1[e] = 0.f; }

        const f16x8* bp = ep + (size_t)(lkg * 1024 + c0);  // +ks*2048; tile1 +32; lo +32768
        f16x8 Bh0 = bp[0], Bh1 = bp[32], Bl0 = bp[32768], Bl1 = bp[32768 + 32];

        #pragma unroll 2
        for (int ks = 0; ks < 16; ++ks) {
            f16x8 ah = *(const f16x8*)&apack[(ks * 2 + lkg) * 32 + lrow];
            f16x8 al = *(const f16x8*)&apack[((16 + ks) * 2 + lkg) * 32 + lrow];
            // depth-1 B prefetch (last iter harmlessly reloads ks=0)
            const f16x8* nb = bp + (size_t)(((ks + 1) & 15) * 2048);
            f16x8 nh0 = nb[0], nh1 = nb[32], nl0 = nb[32768], nl1 = nb[32768 + 32];
            acc0 = __builtin_amdgcn_mfma_f32_32x32x16_f16(ah, Bh0, acc0, 0, 0, 0);
            acc1 = __builtin_amdgcn_mfma_f32_32x32x16_f16(ah, Bh1, acc1, 0, 0, 0);
            acc0 = __builtin_amdgcn_mfma_f32_32x32x16_f16(ah, Bl0, acc0, 0, 0, 0);
            acc1 = __builtin_amdgcn_mfma_f32_32x32x16_f16(ah, Bl1, acc1, 0, 0, 0);
            acc0 = __builtin_amdgcn_mfma_f32_32x32x16_f16(al, Bh0, acc0, 0, 0, 0);
            acc1 = __builtin_amdgcn_mfma_f32_32x32x16_f16(al, Bh1, acc1, 0, 0, 0);
            Bh0 = nh0; Bh1 = nh1; Bl0 = nl0; Bl1 = nl1;
        }

        // prefetch gumbel for tile1, then fused epilogues
        float g1r[16];
        #pragma unroll
        for (int reg = 0; reg < 16; ++reg) {
            int row = (reg & 3) + 8 * (reg >> 2) + 4 * lkg;
            g1r[reg] = gb[((size_t)row << 10) + 32];
        }

        // ---- epilogue tile0: distances, gumbel argmax, KLD ----
        {
            const float e2c = e2[c0];
            #pragma unroll
            for (int reg = 0; reg < 16; ++reg) {
                int row = (reg & 3) + 8 * (reg >> 2) + 4 * lkg;
                float dist = xn2[row] + e2c - 2.f * acc0[reg];
                float val  = g0r[reg] - dist;
                if (val > rv[reg]) { rv[reg] = val; ri[reg] = c0; }
                float p = 1.f / (1.f + __expf(dist));
                kld_acc += p * __logf(fmaxf(p, 1e-8f));
            }
        }
        // ---- epilogue tile1 ----
        {
            const float e2c = e2[c0 + 32];
            #pragma unroll
            for (int reg = 0; reg < 16; ++reg) {
                int row = (reg & 3) + 8 * (reg >> 2) + 4 * lkg;
                float dist = xn2[row] + e2c - 2.f * acc1[reg];
                float val  = g1r[reg] - dist;
                if (val > rv[reg]) { rv[reg] = val; ri[reg] = c0 + 32; }
                float p = 1.f / (1.f + __expf(dist));
                kld_acc += p * __logf(fmaxf(p, 1e-8f));
            }
        }
    }

    // ---- per-row argmax: reduce across the 32 col-lanes (first-index tie-break) ----
    #pragma unroll
    for (int reg = 0; reg < 16; ++reg) {
        float v = rv[reg];
        int   c = ri[reg];
        #pragma unroll
        for (int off = 16; off > 0; off >>= 1) {
            float ov = __shfl_xor(v, off, 64);
            int   oc = __shfl_xor(c, off, 64);
            if (ov > v || (ov == v && oc < c)) { v = ov; c = oc; }
        }
        if (lrow == 0) {
            int row = (reg & 3) + 8 * (reg >> 2) + 4 * lkg;
            rrv[row][wv] = v;
            rri[row][wv] = c;
        }
    }
    __syncthreads();
    // combine the 4 waves' partials (wave order = ascending col ranges)
    if (tid < BM) {
        float bv = rrv[tid][0]; int bc = rri[tid][0];
        #pragma unroll
        for (int w = 1; w < 4; ++w) {
            float v = rrv[tid][w]; int c = rri[tid][w];
            if (v > bv || (v == bv && c < bc)) { bv = v; bc = c; }
        }
        idxs[tid] = bc;
        atomicAdd(&counts[bc], 1.0f);
    }
    __syncthreads();

    // ---- encodings: one-hot, fully coalesced float4 stores ----
    {
        float* enc = out + ENC_OFF;
        for (int t = tid; t < BM * (KCODES / 4); t += 256) {
            int c4 = t & 255, row = t >> 8;
            int base = c4 * 4;
            int id = idxs[row];
            float4 v;
            v.x = (base + 0 == id) ? 1.f : 0.f;
            v.y = (base + 1 == id) ? 1.f : 0.f;
            v.z = (base + 2 == id) ? 1.f : 0.f;
            v.w = (base + 3 == id) ? 1.f : 0.f;
            *(float4*)(enc + ((size_t)(n0 + row) << 10) + base) = v;
        }
    }

    // ---- quantized gather + store (NCHW) + e_latent partial (x re-read from global) ----
    float elat_acc = 0.f;
    {
        float* outq = out + QUANT_OFF;
        for (int t = tid; t < DDIM * (BM / 4); t += 256) {  // (c, r4)
            int r4 = t & 7, c = t >> 3;
            float4 xv = *(const float4*)(inp + (((size_t)(b * DDIM + c)) << 10) + s0 + r4 * 4);
            float q0 = emb[(size_t)idxs[r4 * 4 + 0] * DDIM + c];
            float q1 = emb[(size_t)idxs[r4 * 4 + 1] * DDIM + c];
            float q2 = emb[(size_t)idxs[r4 * 4 + 2] * DDIM + c];
            float q3 = emb[(size_t)idxs[r4 * 4 + 3] * DDIM + c];
            float d0 = q0 - xv.x, d1 = q1 - xv.y, d2 = q2 - xv.z, d3 = q3 - xv.w;
            elat_acc = fmaf(d0, d0, elat_acc);
            elat_acc = fmaf(d1, d1, elat_acc);
            elat_acc = fmaf(d2, d2, elat_acc);
            elat_acc = fmaf(d3, d3, elat_acc);
            float4 qv = make_float4(q0, q1, q2, q3);
            *(float4*)(outq + (((size_t)(b * DDIM + c)) << 10) + s0 + r4 * 4) = qv;
        }
    }

    // ---- block-reduce kld & elat, one atomic each per block ----
    #pragma unroll
    for (int off = 32; off > 0; off >>= 1) {
        kld_acc  += __shfl_xor(kld_acc, off);
        elat_acc += __shfl_xor(elat_acc, off);
    }
    if ((tid & 63) == 0) { redK[wv] = kld_acc; redE[wv] = elat_acc; }
    __syncthreads();
    if (tid == 0) {
        atomicAdd(&ws[2 * KCODES],     redK[0] + redK[1] + redK[2] + redK[3]);
        atomicAdd(&ws[2 * KCODES + 1], redE[0] + redE[1] + redE[2] + redE[3]);
    }
}

__global__ void __launch_bounds__(256)
vq_finalize(const float* __restrict__ ws, float* __restrict__ out) {
    __shared__ float red[4];
    int tid = threadIdx.x;
    float s = 0.f;
    for (int k = tid; k < KCODES; k += 256) {
        float avg = ws[KCODES + k] * (1.f / (float)NROWS);
        s += avg * logf(avg + 1e-10f);
    }
    #pragma unroll
    for (int off = 32; off > 0; off >>= 1) s += __shfl_xor(s, off);
    if ((tid & 63) == 0) red[tid >> 6] = s;
    __syncthreads();
    if (tid == 0) {
        float ssum = red[0] + red[1] + red[2] + red[3];
        float perp = expf(-ssum);
        float kld  = ws[2 * KCODES]     / (float)NROWS;
        float elat = ws[2 * KCODES + 1] / (float)(NROWS * DDIM);
        float ratio = kld / fmaxf(elat, 1e-8f);
        float loss  = 1.5f * (kld + elat * ratio);
        out[0]        = loss;
        out[PERP_OFF] = perp;
    }
}

extern "C" void kernel_launch(void* const* d_in, const int* in_sizes, int n_in,
                              void* d_out, int out_size, void* d_ws, size_t ws_size,
                              hipStream_t stream) {
    const float* inp = (const float*)d_in[0];   // [32,256,32,32]
    const float* emb = (const float*)d_in[1];   // [1024,256]
    const float* gmb = (const float*)d_in[2];   // [32768,1024]
    float* out = (float*)d_out;
    float* ws  = (float*)d_ws;

    vq_setup<<<dim3(KCODES / 256), dim3(256), 0, stream>>>(emb, ws);
    vq_pack<<<dim3(256), dim3(256), 0, stream>>>(emb, ws);
    vq_main<<<dim3(NROWS / BM), dim3(256), 0, stream>>>(inp, emb, gmb, out, ws);
    vq_finalize<<<dim3(1), dim3(256), 0, stream>>>(ws, out);
}